// Round 1
// baseline (45815.500 us; speedup 1.0000x reference)
//
#include <hip/hip_runtime.h>
#include <cstdint>
#include <cstddef>

// Problem constants
constexpr int B_ = 16, T_ = 200, L_ = 250;
constexpr int IDIM = 512, ODIM = 80, DUNITS = 1024;
constexpr int ADIM = 128, ACH = 32, AK = 31;
constexpr int PRE = 256;

// Workspace layout (float offsets)
constexpr size_t O_PEENC = 0;                       // pe_t  [B][ADIM][T]   (transposed pre_enc)
constexpr size_t O_PREN  = 409600;                  // pren  [B][L][PRE]
constexpr size_t O_M     = 1433600;                 // M     [31][128] folded conv*W_att
constexpr size_t O_ATTW  = 1437696;                 // attw  [2][B][T] ping-pong
constexpr size_t O_ATTC  = 1444096;                 // attc  [B][512]
constexpr size_t O_Z0    = 1452288;                 // z0    [2][B][1024]
constexpr size_t O_Z1    = 1485056;                 // z1    [2][B][1024]
constexpr size_t O_C0    = 1517824;                 // c0    [B][1024]
constexpr size_t O_C1    = 1534208;                 // c1    [B][1024]
constexpr size_t O_Z1ALL = 1550592;                 // z1all [L][B][1024]
constexpr size_t O_OUTS  = 5646592;                 // outs  [B][80][L]  (pre-postnet, BCL)
constexpr size_t O_PA    = 5966592;                 // postnet ping  [B][512][L]
constexpr size_t O_PB    = 8014592;                 // postnet pong  [B][512][L]

__device__ __forceinline__ float fsig(float x) {
  x = fminf(fmaxf(x, -30.f), 30.f);
  return __builtin_amdgcn_rcpf(1.f + __expf(-x));
}
__device__ __forceinline__ float ftanh(float x) {
  x = fminf(fmaxf(x, -15.f), 15.f);
  const float e = __expf(2.f * x);
  return (e - 1.f) * __builtin_amdgcn_rcpf(e + 1.f);
}

// ---------------- prep kernels ----------------

// pre_enc = hs @ W_enc + b_enc, stored TRANSPOSED as [b][a][t] so the
// per-step attention kernel (lane = t) reads it coalesced.
__global__ void k_preenc(const float* __restrict__ hs, const float* __restrict__ W_enc,
                         const float* __restrict__ b_enc, float* __restrict__ pe_t) {
  const int bt = blockIdx.x;
  const int b = bt / T_, t = bt % T_;
  __shared__ float s[IDIM];
  for (int i = threadIdx.x; i < IDIM; i += 128) s[i] = hs[(size_t)bt * IDIM + i];
  __syncthreads();
  const int a = threadIdx.x;
  float acc = b_enc[a];
#pragma unroll 4
  for (int d = 0; d < IDIM; ++d) acc += s[d] * W_enc[d * ADIM + a];
  pe_t[((size_t)b * ADIM + a) * T_ + t] = acc;
}

// M[k][a] = sum_c loc_conv_w[c][k] * W_att[c][a]  (conv+einsum fold)
__global__ void k_precM(const float* __restrict__ lw, const float* __restrict__ W_att,
                        float* __restrict__ Mm) {
  const int k = blockIdx.x, a = threadIdx.x;
  float acc = 0.f;
  for (int c = 0; c < ACH; ++c) acc += lw[c * AK + k] * W_att[c * ADIM + a];
  Mm[k * ADIM + a] = acc;
}

__global__ void k_prenet1(const float* __restrict__ ys, const float* __restrict__ W1,
                          float* __restrict__ h1) {
  const int bl = blockIdx.x, b = bl / L_, l = bl % L_;
  __shared__ float s[ODIM];
  if (threadIdx.x < ODIM)
    s[threadIdx.x] = (l == 0) ? 0.f : ys[((size_t)b * L_ + l - 1) * ODIM + threadIdx.x];
  __syncthreads();
  const int p = threadIdx.x;
  float acc = 0.f;
#pragma unroll 4
  for (int o = 0; o < ODIM; ++o) acc += s[o] * W1[o * PRE + p];
  h1[(size_t)bl * PRE + p] = fmaxf(acc, 0.f);
}

__global__ void k_prenet2(const float* __restrict__ h1, const float* __restrict__ W2,
                          float* __restrict__ pren) {
  const int bl = blockIdx.x;
  __shared__ float s[PRE];
  s[threadIdx.x] = h1[(size_t)bl * PRE + threadIdx.x];
  __syncthreads();
  const int p = threadIdx.x;
  float acc = 0.f;
#pragma unroll 4
  for (int o = 0; o < PRE; ++o) acc += s[o] * W2[o * PRE + p];
  pren[(size_t)bl * PRE + p] = fmaxf(acc, 0.f);
}

__global__ void k_attw0(const int* __restrict__ hlens, float* __restrict__ attw) {
  const int b = blockIdx.x;
  const int hl = hlens[b];
  const float inv = 1.f / (float)hl;
  for (int t = threadIdx.x; t < T_; t += blockDim.x)
    attw[b * T_ + t] = (t < hl) ? inv : 0.f;
}

__global__ void k_zero(float* __restrict__ p, int n4) {
  const int i = blockIdx.x * blockDim.x + threadIdx.x;
  if (i < n4) ((float4*)p)[i] = make_float4(0.f, 0.f, 0.f, 0.f);
}

// ---------------- per-step bodies ----------------

struct AttArgs {
  const float* pe_t; const float* Mm; const float* W_dec;
  const float* gvec_w; const float* gvec_b; const float* z0_in;
  const float* hs; const int* hlens; const float* attw_in;
  float* attw_out; float* attc;
};

__device__ void att_body(const AttArgs a, const int b) {
  __shared__ __align__(16) float s_aw[232];
  __shared__ __align__(16) float s_M[AK * ADIM];
  __shared__ __align__(16) float s_z0[DUNITS];
  __shared__ __align__(16) float s_dp[2][ADIM];
  __shared__ float s_ew[256];
  __shared__ float s_red[8];
  __shared__ float s_bc[2];
  const int tid = threadIdx.x;
  const int hl = a.hlens[b];
  for (int i = tid; i < T_ + AK - 1; i += 256) {
    const int t = i - (AK / 2);
    s_aw[i] = (t >= 0 && t < T_) ? a.attw_in[b * T_ + t] : 0.f;
  }
  for (int i = tid; i < AK * ADIM; i += 256) s_M[i] = a.Mm[i];
  for (int i = tid; i < DUNITS; i += 256) s_z0[i] = a.z0_in[b * DUNITS + i];
  __syncthreads();
  { // dec proj, split over 2 halves of d
    const int aa = tid & 127, half = tid >> 7;
    const float* wd = a.W_dec + (size_t)half * 512 * ADIM;
    const float* zz = s_z0 + half * 512;
    float acc = 0.f;
#pragma unroll 4
    for (int d = 0; d < 512; ++d) acc += zz[d] * wd[d * ADIM + aa];
    s_dp[half][aa] = acc;
  }
  __syncthreads();
  if (tid < T_) {
    const int t = tid;
    float aw[AK];
#pragma unroll
    for (int k = 0; k < AK; ++k) aw[k] = s_aw[t + k];
    const float* pe = a.pe_t + (size_t)b * ADIM * T_ + t;
    float e = 0.f;
    for (int a4 = 0; a4 < ADIM; a4 += 4) {
      float4 v;
      v.x = s_dp[0][a4 + 0] + s_dp[1][a4 + 0];
      v.y = s_dp[0][a4 + 1] + s_dp[1][a4 + 1];
      v.z = s_dp[0][a4 + 2] + s_dp[1][a4 + 2];
      v.w = s_dp[0][a4 + 3] + s_dp[1][a4 + 3];
#pragma unroll
      for (int k = 0; k < AK; ++k) {
        const float4 m = *(const float4*)&s_M[k * ADIM + a4];
        v.x += aw[k] * m.x; v.y += aw[k] * m.y;
        v.z += aw[k] * m.z; v.w += aw[k] * m.w;
      }
      v.x += pe[(size_t)(a4 + 0) * T_]; v.y += pe[(size_t)(a4 + 1) * T_];
      v.z += pe[(size_t)(a4 + 2) * T_]; v.w += pe[(size_t)(a4 + 3) * T_];
      e += a.gvec_w[a4 + 0] * ftanh(v.x) + a.gvec_w[a4 + 1] * ftanh(v.y)
         + a.gvec_w[a4 + 2] * ftanh(v.z) + a.gvec_w[a4 + 3] * ftanh(v.w);
    }
    s_ew[tid] = e + a.gvec_b[0];
  }
  __syncthreads();
  const float val = (tid < hl) ? 2.f * s_ew[tid] : -3.0e38f;
  float m = val;
#pragma unroll
  for (int o = 32; o > 0; o >>= 1) m = fmaxf(m, __shfl_xor(m, o));
  if ((tid & 63) == 0) s_red[tid >> 6] = m;
  __syncthreads();
  if (tid == 0) s_bc[0] = fmaxf(fmaxf(s_red[0], s_red[1]), fmaxf(s_red[2], s_red[3]));
  __syncthreads();
  const float mm = s_bc[0];
  const float p = (tid < hl) ? __expf(val - mm) : 0.f;
  float ssum = p;
#pragma unroll
  for (int o = 32; o > 0; o >>= 1) ssum += __shfl_xor(ssum, o);
  if ((tid & 63) == 0) s_red[4 + (tid >> 6)] = ssum;
  __syncthreads();
  if (tid == 0) s_bc[1] = __builtin_amdgcn_rcpf(s_red[4] + s_red[5] + s_red[6] + s_red[7]);
  __syncthreads();
  const float w = p * s_bc[1];
  if (tid < T_) { s_ew[tid] = w; a.attw_out[b * T_ + tid] = w; }
  __syncthreads();
  // att_c = w @ hs   (each thread: 2 of 512 dims)
  const float* hsb = a.hs + (size_t)b * T_ * IDIM;
  float c0 = 0.f, c1 = 0.f;
  for (int t = 0; t < hl; ++t) {
    const float ww = s_ew[t];
    c0 += ww * hsb[(size_t)t * IDIM + tid];
    c1 += ww * hsb[(size_t)t * IDIM + 256 + tid];
  }
  a.attc[b * IDIM + tid] = c0;
  a.attc[b * IDIM + 256 + tid] = c1;
}

struct LstmArgs {
  const float* Wih; const float* Whh; const float* bias;
  const float* xA; int strideA; int KA;
  const float* xB; int strideB; int KB;
  const float* h_in; float* c; float* h_out; float* z_store;
};

// Block = 4 hidden units (x4 gates = 16 rows) x 16 batch. Thread (row, b)
// computes one full gate dot. 256-float k-chunks staged in LDS.
__device__ void lstm_body(const LstmArgs p, const int u0) {
  __shared__ __align__(16) float s_x[16][260];
  __shared__ float s_g[16][17];
  const int tid = threadIdx.x;
  const int rl = tid >> 4;          // 0..15 row-local
  const int b = tid & 15;
  const int g = rl >> 2, ul = rl & 3;
  const int r = g * DUNITS + u0 + ul;
  const int Kih = p.KA + p.KB;
  const int nch = (Kih + DUNITS) >> 8;
  const float* wih_row = p.Wih + (size_t)r * Kih;
  const float* whh_row = p.Whh + (size_t)r * DUNITS;
  float4 acc = make_float4(0.f, 0.f, 0.f, 0.f);
  for (int ch = 0; ch < nch; ++ch) {
    const int kg0 = ch << 8;
    __syncthreads();
    const float* src; int sstr;
    if (kg0 < p.KA)     { src = p.xA + kg0;            sstr = p.strideA; }
    else if (kg0 < Kih) { src = p.xB + (kg0 - p.KA);   sstr = p.strideB; }
    else                { src = p.h_in + (kg0 - Kih);  sstr = DUNITS; }
    for (int i = tid; i < 16 * 256; i += 256)
      s_x[i >> 8][i & 255] = src[(size_t)(i >> 8) * sstr + (i & 255)];
    __syncthreads();
    const float* wrow = (kg0 < Kih) ? (wih_row + kg0) : (whh_row + (kg0 - Kih));
    const float4* w4 = (const float4*)wrow;
    const float4* x4 = (const float4*)(&s_x[b][0]);
#pragma unroll 8
    for (int k = 0; k < 64; ++k) {
      const float4 wv = w4[k], xv = x4[k];
      acc.x += wv.x * xv.x; acc.y += wv.y * xv.y;
      acc.z += wv.z * xv.z; acc.w += wv.w * xv.w;
    }
  }
  s_g[rl][b] = acc.x + acc.y + acc.z + acc.w + p.bias[r];
  __syncthreads();
  if (tid < 64) {
    const int u_l = tid >> 4, bb = tid & 15;
    const float xi = s_g[0 * 4 + u_l][bb];
    const float xf = s_g[1 * 4 + u_l][bb];
    const float xg = s_g[2 * 4 + u_l][bb];
    const float xo = s_g[3 * 4 + u_l][bb];
    const int idx = bb * DUNITS + u0 + u_l;
    const float cn = fsig(xf) * p.c[idx] + fsig(xi) * ftanh(xg);
    const float hn = fsig(xo) * ftanh(cn);
    p.c[idx] = cn;
    p.h_out[idx] = hn;
    if (p.z_store) p.z_store[idx] = hn;
  }
}

__global__ void __launch_bounds__(256) k_att(const AttArgs ap) { att_body(ap, blockIdx.x); }
__global__ void __launch_bounds__(256) k_lstm(const LstmArgs lp) { lstm_body(lp, blockIdx.x * 4); }
// LSTM1(t) and attention(t+1) are independent -> one kernel, overlap + 1 fewer launch
__global__ void __launch_bounds__(256) k_fused(const LstmArgs lp, const AttArgs ap, const int do_att) {
  if (blockIdx.x < 256) lstm_body(lp, blockIdx.x * 4);
  else if (do_att) att_body(ap, blockIdx.x - 256);
}

// ---------------- output heads + postnet ----------------

__global__ void __launch_bounds__(128) k_heads(const float* __restrict__ z1_all,
    const float* __restrict__ feat_W, const float* __restrict__ prob_W,
    const float* __restrict__ prob_b, float* __restrict__ out1,
    float* __restrict__ probs, float* __restrict__ outs_bct) {
  const int bl = blockIdx.x, b = bl / L_, l = bl % L_;
  __shared__ float s_z[DUNITS];
  const float* z = z1_all + ((size_t)l * B_ + b) * DUNITS;
  for (int i = threadIdx.x; i < DUNITS; i += 128) s_z[i] = z[i];
  __syncthreads();
  const int co = threadIdx.x;
  if (co < ODIM) {
    float acc = 0.f;
#pragma unroll 4
    for (int d = 0; d < DUNITS; ++d) acc += s_z[d] * feat_W[d * ODIM + co];
    out1[((size_t)b * L_ + l) * ODIM + co] = acc;
    outs_bct[((size_t)b * ODIM + co) * L_ + l] = acc;
  } else if (co == 96) {
    float acc = prob_b[0];
#pragma unroll 4
    for (int d = 0; d < DUNITS; ++d) acc += s_z[d] * prob_W[d];
    probs[(size_t)b * L_ + l] = acc;
  }
}

// conv1d K=5 pad=2 over [B][Cin][L] -> [B][Cout][L]; BN folded to gamma*x+beta.
// Block: fixed b, 8 co, all 250 l. Thread: 4 co x 2 l. s_w reads are wave-uniform.
template <bool TANH, bool FINAL>
__global__ void __launch_bounds__(256) k_conv(const float* __restrict__ x,
    const float* __restrict__ w, const float* __restrict__ gamma,
    const float* __restrict__ beta, float* __restrict__ y,
    const float* __restrict__ res, float* __restrict__ out0,
    const int Cin, const int Cout) {
  const int b = blockIdx.x;
  const int co0 = blockIdx.y * 8;
  const int tid = threadIdx.x;
  const int l = tid & 127;
  const int cg = tid >> 7;
  __shared__ float s_x[8][260];
  __shared__ float s_w[8][8][5];
  float acc[4][2] = {{0.f, 0.f}, {0.f, 0.f}, {0.f, 0.f}, {0.f, 0.f}};
  for (int ci0 = 0; ci0 < Cin; ci0 += 8) {
    __syncthreads();
    for (int i = tid; i < 8 * 260; i += 256) {
      const int ci = i / 260, col = i % 260;
      const int ll = col - 2;
      s_x[ci][col] = (ll >= 0 && ll < L_) ? x[((size_t)b * Cin + ci0 + ci) * L_ + ll] : 0.f;
    }
    for (int i = tid; i < 8 * 8 * 5; i += 256) {
      const int ci = i / 40, rem = i % 40, cl = rem / 5, k = rem % 5;
      s_w[ci][cl][k] = w[((size_t)(co0 + cl) * Cin + ci0 + ci) * 5 + k];
    }
    __syncthreads();
#pragma unroll 2
    for (int ci = 0; ci < 8; ++ci) {
      float xv0[5], xv1[5];
#pragma unroll
      for (int k = 0; k < 5; ++k) { xv0[k] = s_x[ci][l + k]; xv1[k] = s_x[ci][l + 128 + k]; }
#pragma unroll
      for (int j = 0; j < 4; ++j) {
        const int cl = cg * 4 + j;
#pragma unroll
        for (int k = 0; k < 5; ++k) {
          const float ww = s_w[ci][cl][k];
          acc[j][0] += ww * xv0[k];
          acc[j][1] += ww * xv1[k];
        }
      }
    }
  }
#pragma unroll
  for (int j = 0; j < 4; ++j) {
    const int co = co0 + cg * 4 + j;
    const float gm = gamma[co], bt = beta[co];
#pragma unroll
    for (int h = 0; h < 2; ++h) {
      const int ll = l + h * 128;
      if (ll < L_) {
        float v = gm * acc[j][h] + bt;
        if (TANH) v = ftanh(v);
        if (FINAL) out0[((size_t)b * L_ + ll) * ODIM + co] =
                       res[((size_t)b * ODIM + co) * L_ + ll] + v;
        else y[((size_t)b * Cout + co) * L_ + ll] = v;
      }
    }
  }
}

// ---------------- launch ----------------

extern "C" void kernel_launch(void* const* d_in, const int* in_sizes, int n_in,
                              void* d_out, int out_size, void* d_ws, size_t ws_size,
                              hipStream_t stream) {
  const float* hs    = (const float*)d_in[0];
  const int*   hlens = (const int*)d_in[1];
  const float* ys    = (const float*)d_in[2];
  const float* W_enc = (const float*)d_in[3];
  const float* b_enc = (const float*)d_in[4];
  const float* W_dec = (const float*)d_in[5];
  const float* W_att = (const float*)d_in[6];
  const float* lconv = (const float*)d_in[7];
  const float* gvw   = (const float*)d_in[8];
  const float* gvb   = (const float*)d_in[9];
  const float* pW1   = (const float*)d_in[10];
  const float* pW2   = (const float*)d_in[11];
  const float* Wih0  = (const float*)d_in[12];
  const float* Whh0  = (const float*)d_in[13];
  const float* b0    = (const float*)d_in[14];
  const float* Wih1  = (const float*)d_in[15];
  const float* Whh1  = (const float*)d_in[16];
  const float* b1    = (const float*)d_in[17];
  const float* featW = (const float*)d_in[18];
  const float* probW = (const float*)d_in[19];
  const float* probB = (const float*)d_in[20];
  const float* pwin  = (const float*)d_in[21];
  const float* pgin  = (const float*)d_in[22];
  const float* pbin  = (const float*)d_in[23];
  const float* pwmid = (const float*)d_in[24];
  const float* pgmid = (const float*)d_in[25];
  const float* pbmid = (const float*)d_in[26];
  const float* pwout = (const float*)d_in[27];
  const float* pgout = (const float*)d_in[28];
  const float* pbout = (const float*)d_in[29];

  float* ws = (float*)d_ws;
  float* pe_t  = ws + O_PEENC;
  float* pren  = ws + O_PREN;
  float* Mm    = ws + O_M;
  float* attw  = ws + O_ATTW;
  float* attc  = ws + O_ATTC;
  float* z0    = ws + O_Z0;
  float* z1    = ws + O_Z1;
  float* c0    = ws + O_C0;
  float* c1    = ws + O_C1;
  float* z1all = ws + O_Z1ALL;
  float* outsb = ws + O_OUTS;
  float* pa    = ws + O_PA;
  float* pb    = ws + O_PB;

  float* out0 = (float*)d_out;
  float* out1 = out0 + (size_t)B_ * L_ * ODIM;
  float* out2 = out1 + (size_t)B_ * L_ * ODIM;

  hipLaunchKernelGGL(k_preenc, dim3(B_ * T_), dim3(128), 0, stream, hs, W_enc, b_enc, pe_t);
  hipLaunchKernelGGL(k_precM, dim3(AK), dim3(ADIM), 0, stream, lconv, W_att, Mm);
  hipLaunchKernelGGL(k_prenet1, dim3(B_ * L_), dim3(PRE), 0, stream, ys, pW1, pa);
  hipLaunchKernelGGL(k_prenet2, dim3(B_ * L_), dim3(PRE), 0, stream, pa, pW2, pren);
  hipLaunchKernelGGL(k_zero, dim3(96), dim3(256), 0, stream, z0, 98304 / 4);
  hipLaunchKernelGGL(k_attw0, dim3(B_), dim3(256), 0, stream, hlens, attw);

  // attention step 0 (reads attw buf0 + zero z0 buf0, writes attw buf1 + attc)
  const AttArgs a0{pe_t, Mm, W_dec, gvw, gvb, z0, hs, hlens,
                   attw, attw + B_ * T_, attc};
  hipLaunchKernelGGL(k_att, dim3(B_), dim3(256), 0, stream, a0);

  for (int t = 0; t < L_; ++t) {
    const int pi = t & 1, po = 1 - pi;
    const LstmArgs l0{Wih0, Whh0, b0,
                      attc, IDIM, IDIM,
                      pren + (size_t)t * PRE, L_ * PRE, PRE,
                      z0 + (size_t)pi * B_ * DUNITS, c0,
                      z0 + (size_t)po * B_ * DUNITS, nullptr};
    hipLaunchKernelGGL(k_lstm, dim3(256), dim3(256), 0, stream, l0);
    const LstmArgs l1{Wih1, Whh1, b1,
                      z0 + (size_t)po * B_ * DUNITS, DUNITS, DUNITS,
                      nullptr, 0, 0,
                      z1 + (size_t)pi * B_ * DUNITS, c1,
                      z1 + (size_t)po * B_ * DUNITS, z1all + (size_t)t * B_ * DUNITS};
    const AttArgs an{pe_t, Mm, W_dec, gvw, gvb, z0 + (size_t)po * B_ * DUNITS, hs, hlens,
                     attw + (size_t)po * B_ * T_, attw + (size_t)pi * B_ * T_, attc};
    hipLaunchKernelGGL(k_fused, dim3(272), dim3(256), 0, stream, l1, an, (t + 1 < L_) ? 1 : 0);
  }

  hipLaunchKernelGGL(k_heads, dim3(B_ * L_), dim3(128), 0, stream,
                     z1all, featW, probW, probB, out1, out2, outsb);

  hipLaunchKernelGGL((k_conv<true, false>), dim3(B_, 64), dim3(256), 0, stream,
                     outsb, pwin, pgin, pbin, pa, nullptr, nullptr, ODIM, 512);
  hipLaunchKernelGGL((k_conv<true, false>), dim3(B_, 64), dim3(256), 0, stream,
                     pa, pwmid, pgmid, pbmid, pb, nullptr, nullptr, 512, 512);
  hipLaunchKernelGGL((k_conv<true, false>), dim3(B_, 64), dim3(256), 0, stream,
                     pb, pwmid + (size_t)512 * 512 * 5, pgmid + 512, pbmid + 512,
                     pa, nullptr, nullptr, 512, 512);
  hipLaunchKernelGGL((k_conv<true, false>), dim3(B_, 64), dim3(256), 0, stream,
                     pa, pwmid + (size_t)2 * 512 * 512 * 5, pgmid + 1024, pbmid + 1024,
                     pb, nullptr, nullptr, 512, 512);
  hipLaunchKernelGGL((k_conv<false, true>), dim3(B_, 10), dim3(256), 0, stream,
                     pb, pwout, pgout, pbout, nullptr, outsb, out0, 512, ODIM);
}

// Round 2
// 24242.049 us; speedup vs baseline: 1.8899x; 1.8899x over previous
//
#include <hip/hip_runtime.h>
#include <cstdint>
#include <cstddef>

// Problem constants
constexpr int B_ = 16, T_ = 200, L_ = 250;
constexpr int IDIM = 512, ODIM = 80, DUNITS = 1024;
constexpr int ADIM = 128, ACH = 32, AK = 31;
constexpr int PRE = 256;
constexpr int TPAD = 208;   // T padded to 13*16 for MFMA t-tiles

typedef _Float16 h16;
typedef _Float16 half8 __attribute__((ext_vector_type(8)));
typedef _Float16 half4 __attribute__((ext_vector_type(4)));
typedef _Float16 half2v __attribute__((ext_vector_type(2)));
typedef float f32x4 __attribute__((ext_vector_type(4)));

// ---- workspace byte offsets (all 16B-aligned) ----
constexpr size_t OFF_PE    = 0;         // pe_h   [16][128][208] f16 (zero-padded t>=200)
constexpr size_t OFF_H0H   = 851968;    // h0h    [2][16][1024] f16   (z0 pingpong)
constexpr size_t OFF_Z1H   = 917504;    // z1h    [2][16][1024] f16
constexpr size_t OFF_C0    = 983040;    // c0     [16][1024] f32
constexpr size_t OFF_C1    = 1048576;   // c1     [16][1024] f32
constexpr size_t OFF_DP    = 1114112;   // dp     [16][128] f32  (z0 @ W_dec)
constexpr size_t OFF_FLAGS = 1122304;   // flags  [256] int
constexpr size_t ZERO_BYTES= 1123328;   // zero span [0, here)
constexpr size_t OFF_ATTW  = 1123328;   // attw   [2][16][200] f32
constexpr size_t OFF_ATTC  = 1148928;   // attc_h [16][512] f16
constexpr size_t OFF_MB    = 1165312;   // Mb     [8][64][8] f16 (B-frag packed conv*W_att)
constexpr size_t OFF_PREN  = 1173504;   // pren_h [250][16][256] f16
constexpr size_t OFF_HSH   = 3221504;   // hs_h   [16][200][512] f16
constexpr size_t OFF_W0H   = 6498304;   // W0h    [4096][1792] f16 (rows u*4+g)
constexpr size_t OFF_W1H   = 21178368;  // W1h    [4224][2048] f16 (rows u*4+g; 4096+: Wdec cols)
constexpr size_t OFF_Z1ALL = 38479872;  // z1all  [250][16][1024] f32
constexpr size_t OFF_OUTS  = 54863872;  // outs   [16][80][250] f32
constexpr size_t OFF_PA    = 56143872;  // postnet ping [16][512][250] f32
constexpr size_t OFF_PB    = 64335872;  // postnet pong

__device__ __forceinline__ float fsig(float x) {
  x = fminf(fmaxf(x, -30.f), 30.f);
  return __builtin_amdgcn_rcpf(1.f + __expf(-x));
}
__device__ __forceinline__ float ftanh(float x) {
  x = fminf(fmaxf(x, -15.f), 15.f);
  const float e = __expf(2.f * x);
  return (e - 1.f) * __builtin_amdgcn_rcpf(e + 1.f);
}
__device__ __forceinline__ f32x4 mfma16(half8 a, half8 b, f32x4 c) {
  return __builtin_amdgcn_mfma_f32_16x16x32_f16(a, b, c, 0, 0, 0);
}

// ---------------- prep kernels ----------------

__global__ void k_zero(float4* __restrict__ p, int n4) {
  const int i = blockIdx.x * blockDim.x + threadIdx.x;
  if (i < n4) p[i] = make_float4(0.f, 0.f, 0.f, 0.f);
}

__global__ void k_attw0(const int* __restrict__ hlens, float* __restrict__ attw) {
  const int b = blockIdx.x;
  const int hl = hlens[b];
  const float inv = 1.f / (float)hl;
  for (int t = threadIdx.x; t < T_; t += blockDim.x)
    attw[b * T_ + t] = (t < hl) ? inv : 0.f;
}

// pe_enc = hs @ W_enc + b_enc -> f16, layout [b][a][208] (t-major for half4 loads)
__global__ void __launch_bounds__(128) k_preenc(const float* __restrict__ hs,
    const float* __restrict__ W_enc, const float* __restrict__ b_enc,
    h16* __restrict__ pe_h) {
  const int bt = blockIdx.x, b = bt / T_, tt = bt % T_;
  __shared__ float s[IDIM];
  for (int i = threadIdx.x; i < IDIM; i += 128) s[i] = hs[(size_t)bt * IDIM + i];
  __syncthreads();
  const int a = threadIdx.x;
  float acc = b_enc[a];
#pragma unroll 4
  for (int d = 0; d < IDIM; ++d) acc += s[d] * W_enc[d * ADIM + a];
  pe_h[((size_t)b * ADIM + a) * TPAD + tt] = (h16)acc;
}

// Mb: conv-fold matrix M[k][a] = sum_c lconv[c][k] W_att[c][a], packed in MFMA
// B-frag order: Mb[(at*64+lane)*8 + j] = M[8*(lane>>4)+j][at*16 + (lane&15)], k=31 padded 0
__global__ void k_precMb(const float* __restrict__ lconv, const float* __restrict__ W_att,
                         h16* __restrict__ Mb) {
  const int at = blockIdx.x, lane = threadIdx.x;   // 8 blocks x 64 threads
  const int a = at * 16 + (lane & 15);
  const int k0 = (lane >> 4) * 8;
  half8 o;
#pragma unroll
  for (int j = 0; j < 8; ++j) {
    const int k = k0 + j;
    float v = 0.f;
    if (k < AK)
      for (int c = 0; c < ACH; ++c) v += lconv[c * AK + k] * W_att[c * ADIM + a];
    o[j] = (h16)v;
  }
  *(half8*)(Mb + (size_t)(at * 64 + lane) * 8) = o;
}

// W0h[u*4+g][k] = k<768 ? Wih0[g*1024+u][k] : Whh0[g*1024+u][k-768]
__global__ void k_cvt_w0(const float* __restrict__ Wih0, const float* __restrict__ Whh0,
                         h16* __restrict__ W0h) {
  const int rr = blockIdx.x;
  const int u = rr >> 2, g = rr & 3;
  const int orig = g * 1024 + u;
  const float* ih = Wih0 + (size_t)orig * 768;
  const float* hh = Whh0 + (size_t)orig * 1024;
  h16* out = W0h + (size_t)rr * 1792;
  for (int k = threadIdx.x; k < 1792; k += 256)
    out[k] = (h16)(k < 768 ? ih[k] : hh[k - 768]);
}

// W1h rows 0..4095: [Wih1 | Whh1] gate-permuted; rows 4096..4223: [W_dec[:,a] | 0]
__global__ void k_cvt_w1(const float* __restrict__ Wih1, const float* __restrict__ Whh1,
                         const float* __restrict__ Wdec, h16* __restrict__ W1h) {
  const int rr = blockIdx.x;
  h16* out = W1h + (size_t)rr * 2048;
  if (rr < 4096) {
    const int u = rr >> 2, g = rr & 3;
    const int orig = g * 1024 + u;
    const float* ih = Wih1 + (size_t)orig * 1024;
    const float* hh = Whh1 + (size_t)orig * 1024;
    for (int k = threadIdx.x; k < 2048; k += 256)
      out[k] = (h16)(k < 1024 ? ih[k] : hh[k - 1024]);
  } else {
    const int a = rr - 4096;
    for (int k = threadIdx.x; k < 2048; k += 256)
      out[k] = (h16)(k < 1024 ? Wdec[(size_t)k * ADIM + a] : 0.f);
  }
}

__global__ void k_cvt_hs(const float* __restrict__ hs, h16* __restrict__ hs_h) {
  const size_t i = ((size_t)blockIdx.x * 256 + threadIdx.x) * 4;
  const float4 v = *(const float4*)(hs + i);
  half4 o; o[0] = (h16)v.x; o[1] = (h16)v.y; o[2] = (h16)v.z; o[3] = (h16)v.w;
  *(half4*)(hs_h + i) = o;
}

__global__ void k_prenet1(const float* __restrict__ ys, const float* __restrict__ W1,
                          float* __restrict__ h1) {
  const int bl = blockIdx.x, b = bl / L_, l = bl % L_;
  __shared__ float s[ODIM];
  if (threadIdx.x < ODIM)
    s[threadIdx.x] = (l == 0) ? 0.f : ys[((size_t)b * L_ + l - 1) * ODIM + threadIdx.x];
  __syncthreads();
  const int p = threadIdx.x;
  float acc = 0.f;
#pragma unroll 4
  for (int o = 0; o < ODIM; ++o) acc += s[o] * W1[o * PRE + p];
  h1[(size_t)bl * PRE + p] = fmaxf(acc, 0.f);
}

// writes f16, layout [l][b][256]
__global__ void k_prenet2h(const float* __restrict__ h1, const float* __restrict__ W2,
                           h16* __restrict__ pren_h) {
  const int bl = blockIdx.x, b = bl / L_, ll = bl % L_;
  __shared__ float s[PRE];
  s[threadIdx.x] = h1[(size_t)bl * PRE + threadIdx.x];
  __syncthreads();
  const int p = threadIdx.x;
  float acc = 0.f;
#pragma unroll 4
  for (int o = 0; o < PRE; ++o) acc += s[o] * W2[o * PRE + p];
  pren_h[((size_t)ll * B_ + b) * PRE + p] = (h16)fmaxf(acc, 0.f);
}

// ---------------- attention body (block handles one batch b) ----------------
// All pointers pre-offset for b except flags.
__device__ void att_body2(const h16* __restrict__ pe_h, const h16* __restrict__ Mb,
                          const float* __restrict__ dp, const float* __restrict__ gvw,
                          const float* __restrict__ attw_in, float* __restrict__ attw_out,
                          const h16* __restrict__ hs_b, const int hl,
                          h16* __restrict__ attc_b, int* __restrict__ flags, const int t) {
  __shared__ float s_aw[240];
  __shared__ float s_dp[ADIM];
  __shared__ float s_gv[ADIM];
  __shared__ float s_ew[256];
  __shared__ float s_w[208];
  __shared__ float s_r8[8];
  __shared__ float s_bc[2];
  const int tid = threadIdx.x;
  if (tid < 240) {
    const int tt = tid - (AK / 2);
    s_aw[tid] = (tt >= 0 && tt < T_) ? attw_in[tt] : 0.f;
  }
  if (tid < ADIM) { s_dp[tid] = dp[tid]; s_gv[tid] = gvw[tid]; }
  __syncthreads();
  const int lane = tid & 63, wave = tid >> 6;
  const int l15 = lane & 15, kl8 = (lane >> 4) * 8;
  half8 bfrag[8];
#pragma unroll
  for (int at = 0; at < 8; ++at)
    bfrag[at] = *(const half8*)(Mb + (size_t)(at * 64 + lane) * 8);
  // scores: conv via MFMA [208 t x 32 k] @ [32 k x 128 a], fused tanh-dot
#pragma unroll
  for (int mi = 0; mi < 4; ++mi) {
    const int mt = wave + mi * 4;
    if (mt <= 12) {
      half8 af;
#pragma unroll
      for (int j = 0; j < 8; ++j) af[j] = (h16)s_aw[mt * 16 + l15 + kl8 + j];
      const int t0 = mt * 16 + 4 * (lane >> 4);
      float e0 = 0.f, e1 = 0.f, e2 = 0.f, e3 = 0.f;
#pragma unroll
      for (int at = 0; at < 8; ++at) {
        f32x4 z4 = {0.f, 0.f, 0.f, 0.f};
        const f32x4 cv = mfma16(af, bfrag[at], z4);
        const int a = at * 16 + l15;
        const half4 pe4 = *(const half4*)(pe_h + (size_t)a * TPAD + t0);
        const float g = s_gv[a], d = s_dp[a];
        e0 += g * ftanh(cv[0] + (float)pe4[0] + d);
        e1 += g * ftanh(cv[1] + (float)pe4[1] + d);
        e2 += g * ftanh(cv[2] + (float)pe4[2] + d);
        e3 += g * ftanh(cv[3] + (float)pe4[3] + d);
      }
#pragma unroll
      for (int o = 1; o < 16; o <<= 1) {
        e0 += __shfl_xor(e0, o); e1 += __shfl_xor(e1, o);
        e2 += __shfl_xor(e2, o); e3 += __shfl_xor(e3, o);
      }
      if (l15 == 0) {
        s_ew[t0 + 0] = e0; s_ew[t0 + 1] = e1; s_ew[t0 + 2] = e2; s_ew[t0 + 3] = e3;
      }
    }
  }
  __syncthreads();
  // softmax over t (scale 2.0; gvec_b cancels in softmax)
  const float val = (tid < hl) ? 2.f * s_ew[tid] : -3.0e38f;
  float m = val;
#pragma unroll
  for (int o = 32; o > 0; o >>= 1) m = fmaxf(m, __shfl_xor(m, o));
  if ((tid & 63) == 0) s_r8[tid >> 6] = m;
  __syncthreads();
  if (tid == 0) s_bc[0] = fmaxf(fmaxf(s_r8[0], s_r8[1]), fmaxf(s_r8[2], s_r8[3]));
  __syncthreads();
  const float p = (tid < hl) ? __expf(val - s_bc[0]) : 0.f;
  float ssum = p;
#pragma unroll
  for (int o = 32; o > 0; o >>= 1) ssum += __shfl_xor(ssum, o);
  if ((tid & 63) == 0) s_r8[4 + (tid >> 6)] = ssum;
  __syncthreads();
  if (tid == 0) s_bc[1] = __builtin_amdgcn_rcpf(s_r8[4] + s_r8[5] + s_r8[6] + s_r8[7]);
  __syncthreads();
  if (tid < T_) {
    const float w = p * s_bc[1];
    s_w[tid] = w;
    attw_out[tid] = w;
  }
  __syncthreads();
  // context: att_c[d] = sum_t w[t] hs[t][d], d = 2*tid, 2*tid+1
  float cx0 = 0.f, cx1 = 0.f;
  for (int tt = 0; tt < hl; ++tt) {
    const float w = s_w[tt];
    const half2v hv = *(const half2v*)(hs_b + (size_t)tt * IDIM + 2 * tid);
    cx0 += w * (float)hv[0];
    cx1 += w * (float)hv[1];
  }
  half2v o2; o2[0] = (h16)cx0; o2[1] = (h16)cx1;
  *(half2v*)(attc_b + 2 * tid) = o2;
  __syncthreads();
  if (tid == 0)
    __hip_atomic_fetch_add(flags + t, 1, __ATOMIC_RELEASE, __HIP_MEMORY_SCOPE_AGENT);
}

// ---------------- step kernels ----------------
// k_step1: grid 256 (co-resident). blocks 0-15 also run att(t); all blocks then
// lstm0(t) GEMM (16 gate-rows each, K=1792 split over 4 waves, reg-prefetched W).
__global__ void __launch_bounds__(256) k_step1(
    const h16* __restrict__ W0h, h16* __restrict__ attc_h,
    const h16* __restrict__ pren_h, h16* __restrict__ h0h,
    float* __restrict__ c0, const float* __restrict__ b0,
    const h16* __restrict__ pe_h, const h16* __restrict__ Mb,
    const float* __restrict__ dp, const float* __restrict__ gvw,
    float* __restrict__ attw, const h16* __restrict__ hs_h,
    const int* __restrict__ hlens, int* __restrict__ flags, const int t) {
  const int blk = blockIdx.x, tid = threadIdx.x;
  const int lane = tid & 63, wave = tid >> 6;
  const int nloc = lane & 15, kl8 = (lane >> 4) * 8;
  const int pi = t & 1, po = pi ^ 1;
  // prefetch this block's 16 weight rows (wave's K-slice) into registers
  const h16* wrow = W0h + ((size_t)(blk * 16 + nloc)) * 1792 + wave * 448 + kl8;
  half8 wreg[14];
#pragma unroll
  for (int c = 0; c < 14; ++c) wreg[c] = *(const half8*)(wrow + c * 32);
  __builtin_amdgcn_sched_barrier(0);
  if (blk < B_) {
    att_body2(pe_h + (size_t)blk * ADIM * TPAD, Mb, dp + blk * ADIM, gvw,
              attw + pi * (B_ * T_) + blk * T_, attw + po * (B_ * T_) + blk * T_,
              hs_h + (size_t)blk * T_ * IDIM, hlens[blk],
              attc_h + blk * IDIM, flags, t);
  }
  if (tid == 0) {
    while (__hip_atomic_load(flags + t, __ATOMIC_ACQUIRE, __HIP_MEMORY_SCOPE_AGENT) < B_) {}
  }
  __syncthreads();
  // GEMM: A = x[16 b][K] f16 (attc | pren_t | h), B = wreg
  const h16* hin = h0h + (size_t)pi * (B_ * DUNITS);
  const h16* prent = pren_h + (size_t)t * (B_ * PRE);
  f32x4 acc = {0.f, 0.f, 0.f, 0.f};
#pragma unroll
  for (int c = 0; c < 14; ++c) {
    const int kg = wave * 448 + c * 32;
    const h16* ap;
    if (kg < 512)      ap = attc_h + nloc * IDIM + kg + kl8;
    else if (kg < 768) ap = prent + nloc * PRE + (kg - 512) + kl8;
    else               ap = hin + nloc * DUNITS + (kg - 768) + kl8;
    acc = mfma16(*(const half8*)ap, wreg[c], acc);
  }
  __shared__ float s_red[4][64][4];
  __shared__ float s_g[16][17];
#pragma unroll
  for (int r = 0; r < 4; ++r) s_red[wave][lane][r] = acc[r];
  __syncthreads();
  {
    const int l = tid & 63, r = tid >> 6;
    const float v = s_red[0][l][r] + s_red[1][l][r] + s_red[2][l][r] + s_red[3][l][r];
    s_g[l & 15][4 * (l >> 4) + r] = v;    // s_g[local_row][batch]
  }
  __syncthreads();
  if (tid < 64) {
    const int ul = tid >> 4, b = tid & 15;
    const int u = blk * 4 + ul;
    const float xi = s_g[ul * 4 + 0][b] + b0[u];
    const float xf = s_g[ul * 4 + 1][b] + b0[1024 + u];
    const float xg = s_g[ul * 4 + 2][b] + b0[2048 + u];
    const float xo = s_g[ul * 4 + 3][b] + b0[3072 + u];
    const int idx = b * DUNITS + u;
    const float cn = fsig(xf) * c0[idx] + fsig(xi) * ftanh(xg);
    c0[idx] = cn;
    h0h[(size_t)po * (B_ * DUNITS) + idx] = (h16)(fsig(xo) * ftanh(cn));
  }
}

// k_step2: grid 264. blocks 0-255: lstm1(t); blocks 256-263: dp(t+1)=z0_t@W_dec
__global__ void __launch_bounds__(256) k_step2(
    const h16* __restrict__ W1h, const h16* __restrict__ h0h,
    h16* __restrict__ z1h, float* __restrict__ c1, const float* __restrict__ b1,
    float* __restrict__ z1all, float* __restrict__ dp, const int t) {
  const int blk = blockIdx.x, tid = threadIdx.x;
  const int lane = tid & 63, wave = tid >> 6;
  const int nloc = lane & 15, kl8 = (lane >> 4) * 8;
  const int pi = t & 1, po = pi ^ 1;
  const h16* z0 = h0h + (size_t)po * (B_ * DUNITS);   // z0_t (just written)
  const h16* z1in = z1h + (size_t)pi * (B_ * DUNITS);
  const h16* wrow = W1h + ((size_t)(blk * 16 + nloc)) * 2048 + wave * 512 + kl8;
  half8 wreg[16];
#pragma unroll
  for (int c = 0; c < 16; ++c) wreg[c] = *(const half8*)(wrow + c * 32);
  f32x4 acc = {0.f, 0.f, 0.f, 0.f};
#pragma unroll
  for (int c = 0; c < 16; ++c) {
    const int kg = wave * 512 + c * 32;
    const h16* ap = (kg < 1024) ? (z0 + nloc * DUNITS + kg + kl8)
                                : (z1in + nloc * DUNITS + (kg - 1024) + kl8);
    acc = mfma16(*(const half8*)ap, wreg[c], acc);
  }
  __shared__ float s_red[4][64][4];
  __shared__ float s_g[16][17];
#pragma unroll
  for (int r = 0; r < 4; ++r) s_red[wave][lane][r] = acc[r];
  __syncthreads();
  const int l = tid & 63, r = tid >> 6;
  const float v = s_red[0][l][r] + s_red[1][l][r] + s_red[2][l][r] + s_red[3][l][r];
  if (blk >= 256) {   // dp rows (no bias, no nonlinearity)
    dp[(4 * (l >> 4) + r) * ADIM + (blk - 256) * 16 + (l & 15)] = v;
    return;
  }
  s_g[l & 15][4 * (l >> 4) + r] = v;
  __syncthreads();
  if (tid < 64) {
    const int ul = tid >> 4, b = tid & 15;
    const int u = blk * 4 + ul;
    const float xi = s_g[ul * 4 + 0][b] + b1[u];
    const float xf = s_g[ul * 4 + 1][b] + b1[1024 + u];
    const float xg = s_g[ul * 4 + 2][b] + b1[2048 + u];
    const float xo = s_g[ul * 4 + 3][b] + b1[3072 + u];
    const int idx = b * DUNITS + u;
    const float cn = fsig(xf) * c1[idx] + fsig(xi) * ftanh(xg);
    c1[idx] = cn;
    const float hn = fsig(xo) * ftanh(cn);
    z1h[(size_t)po * (B_ * DUNITS) + idx] = (h16)hn;
    z1all[((size_t)t * B_ + b) * DUNITS + u] = hn;
  }
}

// ---------------- output heads + postnet (unchanged from round 1) ----------------

__global__ void __launch_bounds__(128) k_heads(const float* __restrict__ z1_all,
    const float* __restrict__ feat_W, const float* __restrict__ prob_W,
    const float* __restrict__ prob_b, float* __restrict__ out1,
    float* __restrict__ probs, float* __restrict__ outs_bct) {
  const int bl = blockIdx.x, b = bl / L_, l = bl % L_;
  __shared__ float s_z[DUNITS];
  const float* z = z1_all + ((size_t)l * B_ + b) * DUNITS;
  for (int i = threadIdx.x; i < DUNITS; i += 128) s_z[i] = z[i];
  __syncthreads();
  const int co = threadIdx.x;
  if (co < ODIM) {
    float acc = 0.f;
#pragma unroll 4
    for (int d = 0; d < DUNITS; ++d) acc += s_z[d] * feat_W[d * ODIM + co];
    out1[((size_t)b * L_ + l) * ODIM + co] = acc;
    outs_bct[((size_t)b * ODIM + co) * L_ + l] = acc;
  } else if (co == 96) {
    float acc = prob_b[0];
#pragma unroll 4
    for (int d = 0; d < DUNITS; ++d) acc += s_z[d] * prob_W[d];
    probs[(size_t)b * L_ + l] = acc;
  }
}

template <bool TANH, bool FINAL>
__global__ void __launch_bounds__(256) k_conv(const float* __restrict__ x,
    const float* __restrict__ w, const float* __restrict__ gamma,
    const float* __restrict__ beta, float* __restrict__ y,
    const float* __restrict__ res, float* __restrict__ out0,
    const int Cin, const int Cout) {
  const int b = blockIdx.x;
  const int co0 = blockIdx.y * 8;
  const int tid = threadIdx.x;
  const int l = tid & 127;
  const int cg = tid >> 7;
  __shared__ float s_x[8][260];
  __shared__ float s_w[8][8][5];
  float acc[4][2] = {{0.f, 0.f}, {0.f, 0.f}, {0.f, 0.f}, {0.f, 0.f}};
  for (int ci0 = 0; ci0 < Cin; ci0 += 8) {
    __syncthreads();
    for (int i = tid; i < 8 * 260; i += 256) {
      const int ci = i / 260, col = i % 260;
      const int ll = col - 2;
      s_x[ci][col] = (ll >= 0 && ll < L_) ? x[((size_t)b * Cin + ci0 + ci) * L_ + ll] : 0.f;
    }
    for (int i = tid; i < 8 * 8 * 5; i += 256) {
      const int ci = i / 40, rem = i % 40, cl = rem / 5, k = rem % 5;
      s_w[ci][cl][k] = w[((size_t)(co0 + cl) * Cin + ci0 + ci) * 5 + k];
    }
    __syncthreads();
#pragma unroll 2
    for (int ci = 0; ci < 8; ++ci) {
      float xv0[5], xv1[5];
#pragma unroll
      for (int k = 0; k < 5; ++k) { xv0[k] = s_x[ci][l + k]; xv1[k] = s_x[ci][l + 128 + k]; }
#pragma unroll
      for (int j = 0; j < 4; ++j) {
        const int cl = cg * 4 + j;
#pragma unroll
        for (int k = 0; k < 5; ++k) {
          const float ww = s_w[ci][cl][k];
          acc[j][0] += ww * xv0[k];
          acc[j][1] += ww * xv1[k];
        }
      }
    }
  }
#pragma unroll
  for (int j = 0; j < 4; ++j) {
    const int co = co0 + cg * 4 + j;
    const float gm = gamma[co], bt = beta[co];
#pragma unroll
    for (int h = 0; h < 2; ++h) {
      const int ll = l + h * 128;
      if (ll < L_) {
        float v = gm * acc[j][h] + bt;
        if (TANH) v = ftanh(v);
        if (FINAL) out0[((size_t)b * L_ + ll) * ODIM + co] =
                       res[((size_t)b * ODIM + co) * L_ + ll] + v;
        else y[((size_t)b * Cout + co) * L_ + ll] = v;
      }
    }
  }
}

// ---------------- launch ----------------

extern "C" void kernel_launch(void* const* d_in, const int* in_sizes, int n_in,
                              void* d_out, int out_size, void* d_ws, size_t ws_size,
                              hipStream_t stream) {
  const float* hs    = (const float*)d_in[0];
  const int*   hlens = (const int*)d_in[1];
  const float* ys    = (const float*)d_in[2];
  const float* W_enc = (const float*)d_in[3];
  const float* b_enc = (const float*)d_in[4];
  const float* W_dec = (const float*)d_in[5];
  const float* W_att = (const float*)d_in[6];
  const float* lconv = (const float*)d_in[7];
  const float* gvw   = (const float*)d_in[8];
  const float* pW1   = (const float*)d_in[10];
  const float* pW2   = (const float*)d_in[11];
  const float* Wih0  = (const float*)d_in[12];
  const float* Whh0  = (const float*)d_in[13];
  const float* b0    = (const float*)d_in[14];
  const float* Wih1  = (const float*)d_in[15];
  const float* Whh1  = (const float*)d_in[16];
  const float* b1    = (const float*)d_in[17];
  const float* featW = (const float*)d_in[18];
  const float* probW = (const float*)d_in[19];
  const float* probB = (const float*)d_in[20];
  const float* pwin  = (const float*)d_in[21];
  const float* pgin  = (const float*)d_in[22];
  const float* pbin  = (const float*)d_in[23];
  const float* pwmid = (const float*)d_in[24];
  const float* pgmid = (const float*)d_in[25];
  const float* pbmid = (const float*)d_in[26];
  const float* pwout = (const float*)d_in[27];
  const float* pgout = (const float*)d_in[28];
  const float* pbout = (const float*)d_in[29];

  char* ws = (char*)d_ws;
  h16*   pe_h   = (h16*)(ws + OFF_PE);
  h16*   h0h    = (h16*)(ws + OFF_H0H);
  h16*   z1h    = (h16*)(ws + OFF_Z1H);
  float* c0     = (float*)(ws + OFF_C0);
  float* c1     = (float*)(ws + OFF_C1);
  float* dp     = (float*)(ws + OFF_DP);
  int*   flags  = (int*)(ws + OFF_FLAGS);
  float* attw   = (float*)(ws + OFF_ATTW);
  h16*   attc_h = (h16*)(ws + OFF_ATTC);
  h16*   Mb     = (h16*)(ws + OFF_MB);
  h16*   pren_h = (h16*)(ws + OFF_PREN);
  h16*   hs_h   = (h16*)(ws + OFF_HSH);
  h16*   W0h    = (h16*)(ws + OFF_W0H);
  h16*   W1h    = (h16*)(ws + OFF_W1H);
  float* z1all  = (float*)(ws + OFF_Z1ALL);
  float* outsb  = (float*)(ws + OFF_OUTS);
  float* pa     = (float*)(ws + OFF_PA);
  float* pb     = (float*)(ws + OFF_PB);

  float* out0 = (float*)d_out;
  float* out1 = out0 + (size_t)B_ * L_ * ODIM;
  float* out2 = out1 + (size_t)B_ * L_ * ODIM;

  // prep
  hipLaunchKernelGGL(k_zero, dim3((ZERO_BYTES / 16 + 255) / 256), dim3(256), 0, stream,
                     (float4*)ws, (int)(ZERO_BYTES / 16));
  hipLaunchKernelGGL(k_attw0, dim3(B_), dim3(256), 0, stream, hlens, attw);
  hipLaunchKernelGGL(k_preenc, dim3(B_ * T_), dim3(128), 0, stream, hs, W_enc, b_enc, pe_h);
  hipLaunchKernelGGL(k_precMb, dim3(8), dim3(64), 0, stream, lconv, W_att, Mb);
  hipLaunchKernelGGL(k_cvt_w0, dim3(4096), dim3(256), 0, stream, Wih0, Whh0, W0h);
  hipLaunchKernelGGL(k_cvt_w1, dim3(4224), dim3(256), 0, stream, Wih1, Whh1, W_dec, W1h);
  hipLaunchKernelGGL(k_cvt_hs, dim3(1600), dim3(256), 0, stream, hs, hs_h);
  hipLaunchKernelGGL(k_prenet1, dim3(B_ * L_), dim3(PRE), 0, stream, ys, pW1, pa);
  hipLaunchKernelGGL(k_prenet2h, dim3(B_ * L_), dim3(PRE), 0, stream, pa, pW2, pren_h);

  // scan: 2 launches per step
  for (int t = 0; t < L_; ++t) {
    hipLaunchKernelGGL(k_step1, dim3(256), dim3(256), 0, stream,
                       W0h, attc_h, pren_h, h0h, c0, b0, pe_h, Mb, dp, gvw,
                       attw, hs_h, hlens, flags, t);
    hipLaunchKernelGGL(k_step2, dim3(264), dim3(256), 0, stream,
                       W1h, h0h, z1h, c1, b1, z1all, dp, t);
  }

  hipLaunchKernelGGL(k_heads, dim3(B_ * L_), dim3(128), 0, stream,
                     z1all, featW, probW, probB, out1, out2, outsb);

  hipLaunchKernelGGL((k_conv<true, false>), dim3(B_, 64), dim3(256), 0, stream,
                     outsb, pwin, pgin, pbin, pa, nullptr, nullptr, ODIM, 512);
  hipLaunchKernelGGL((k_conv<true, false>), dim3(B_, 64), dim3(256), 0, stream,
                     pa, pwmid, pgmid, pbmid, pb, nullptr, nullptr, 512, 512);
  hipLaunchKernelGGL((k_conv<true, false>), dim3(B_, 64), dim3(256), 0, stream,
                     pb, pwmid + (size_t)512 * 512 * 5, pgmid + 512, pbmid + 512,
                     pa, nullptr, nullptr, 512, 512);
  hipLaunchKernelGGL((k_conv<true, false>), dim3(B_, 64), dim3(256), 0, stream,
                     pa, pwmid + (size_t)2 * 512 * 512 * 5, pgmid + 1024, pbmid + 1024,
                     pb, nullptr, nullptr, 512, 512);
  hipLaunchKernelGGL((k_conv<false, true>), dim3(B_, 10), dim3(256), 0, stream,
                     pb, pwout, pgout, pbout, nullptr, outsb, out0, 512, ODIM);
}